// Round 1
// 666.440 us; speedup vs baseline: 1.0542x; 1.0542x over previous
//
#include <hip/hip_runtime.h>
#include <hip/hip_bf16.h>
#include <cstdint>
#include <cstddef>

typedef unsigned short u16;
typedef __attribute__((ext_vector_type(8))) __bf16 bf16x8;
typedef __attribute__((ext_vector_type(4))) float f32x4;

#define EPS_BN 1e-5f

__device__ __forceinline__ u16 f2bf(float f) {
    union { float f; uint32_t u; } v; v.f = f;
    uint32_t u = v.u;
    u += 0x7FFFu + ((u >> 16) & 1u);   // round-to-nearest-even
    return (u16)(u >> 16);
}
__device__ __forceinline__ float bf2f(u16 s) {
    union { uint32_t u; float f; } v; v.u = ((uint32_t)s) << 16;
    return v.f;
}

union Pack8 { u16 u[8]; uint4 v4; };
union Pack4 { u16 u[4]; uint2 v2; };

// async global -> LDS, 16B per lane; LDS dest = wave-uniform base + lane*16
typedef __attribute__((address_space(1))) const unsigned char as1c;
typedef __attribute__((address_space(3))) unsigned char as3;
__device__ __forceinline__ void gld_lds16(const void* g, void* l) {
    __builtin_amdgcn_global_load_lds((as1c*)g, (as3*)l, 16, 0, 0);
}

// ---------------------------------------------------------------------------
// Transpose NCHW fp32 -> NHWC bf16 (search + kernel inputs in one launch)
// ---------------------------------------------------------------------------
__device__ __forceinline__ void tr_one(const float* __restrict__ in,
                                       u16* __restrict__ out, int P, int p)
{
    int b = p / P, pp = p - b * P;
    const float* ip = in + (size_t)b * 256 * P + pp;
    u16* op = out + (size_t)p * 256;
    #pragma unroll 4
    for (int cg = 0; cg < 32; cg++) {
        Pack8 pk;
        #pragma unroll
        for (int i = 0; i < 8; i++)
            pk.u[i] = f2bf(ip[(size_t)(cg * 8 + i) * P]);
        *(uint4*)(op + cg * 8) = pk.v4;
    }
}

__global__ __launch_bounds__(256)
void tr_all(const float* __restrict__ s, const float* __restrict__ k,
            u16* __restrict__ so, u16* __restrict__ ko)
{
    int blk = blockIdx.x;
    if (blk < 481) {
        int p = blk * 256 + threadIdx.x;
        if (p < 128 * 961) tr_one(s, so, 961, p);
    } else {
        int p = (blk - 481) * 256 + threadIdx.x;
        if (p < 128 * 49) tr_one(k, ko, 49, p);
    }
}

// ---------------------------------------------------------------------------
// Implicit-im2col GEMM, NHWC bf16 input (old 128x128 / 4-wave structure).
// Kept for stages 1, 4, 5 (small-N or short-K launches).
// ---------------------------------------------------------------------------
template<int TAPS, bool NHWC_OUT, typename OutT, bool RELU>
__global__ __launch_bounds__(256)
void conv_gemm(const u16* __restrict__ in, const u16* __restrict__ W,
               const float* __restrict__ scale, const float* __restrict__ shift,
               OutT* __restrict__ out, int Hi, int Wi, int Ho, int Wo)
{
    constexpr int KT = TAPS * 256;
    constexpr int KB = KT / 64;
    const int HoWo = Ho * Wo;

    __shared__ u16 Alds[8192];   // 16 KB: [row 0..127][128B swizzled]
    __shared__ u16 Blds[8192];   // 16 KB: [pix 0..127][128B swizzled]

    const int tid = threadIdx.x;
    const int it = blockIdx.x;   // I tile (oc): 0..1
    const int jt = blockIdx.y;   // J tile
    const int wv = tid >> 6;
    const int lane = tid & 63;

    const int c8 = tid & 7;
    const int t3 = tid >> 3;
    const int csw = c8 ^ (t3 & 7);     // swizzled global chunk (row&7 == t3&7)

    const u16* gA[4];
    const u16* gB[4];
    #pragma unroll
    for (int q = 0; q < 4; q++) {
        int r = q * 32 + t3;
        gA[q] = W + (size_t)(it * 128 + r) * KT + csw * 8;
        int jg = jt * 128 + r;
        int bb = jg / HoWo;
        int msp = jg - bb * HoWo;
        int oyp = msp / Wo;
        int oxp = msp - oyp * Wo;
        gB[q] = in + ((size_t)(bb * Hi + oyp) * Wi + oxp) * 256 + csw * 8;
    }

    const int wi = (wv >> 1) * 64;
    const int wj = (wv & 1) * 64;
    const int lr = lane & 15;
    const int lq = lane >> 4;

    f32x4 acc[4][4];
    #pragma unroll
    for (int a = 0; a < 4; a++)
        #pragma unroll
        for (int b = 0; b < 4; b++)
            acc[a][b] = (f32x4){0.f, 0.f, 0.f, 0.f};

    for (int kb = 0; kb < KB; kb++) {
        const int tap = (TAPS == 1) ? 0 : (kb >> 2);
        const int c0  = (TAPS == 1) ? (kb * 64) : ((kb & 3) * 64);
        int ky = 0, kx = 0;
        if (TAPS == 9) { ky = tap / 3; kx = tap - ky * 3; }
        const int aoff = tap * 256 + c0;
        const int boff = (ky * Wi + kx) * 256 + c0;
        __syncthreads();
        #pragma unroll
        for (int q = 0; q < 4; q++)
            gld_lds16(gA[q] + aoff, Alds + q * 2048 + wv * 512);
        #pragma unroll
        for (int q = 0; q < 4; q++)
            gld_lds16(gB[q] + boff, Blds + q * 2048 + wv * 512);
        __syncthreads();
        #pragma unroll
        for (int ks = 0; ks < 2; ks++) {
            bf16x8 af[4], bfr[4];
            const int ck = ks * 4 + lq;
            #pragma unroll
            for (int f = 0; f < 4; f++) {
                int ra = wi + f * 16 + lr;
                af[f]  = *(const bf16x8*)&Alds[ra * 64 + ((ck ^ (ra & 7)) * 8)];
                int rb = wj + f * 16 + lr;
                bfr[f] = *(const bf16x8*)&Blds[rb * 64 + ((ck ^ (rb & 7)) * 8)];
            }
            #pragma unroll
            for (int fi = 0; fi < 4; fi++)
                #pragma unroll
                for (int fj = 0; fj < 4; fj++)
                    acc[fi][fj] = __builtin_amdgcn_mfma_f32_16x16x32_bf16(
                        af[fi], bfr[fj], acc[fi][fj], 0, 0, 0);
        }
    }

    if constexpr (NHWC_OUT) {
        int jc[4];
        #pragma unroll
        for (int fj = 0; fj < 4; fj++) jc[fj] = jt * 128 + wj + fj * 16 + lr;
        #pragma unroll
        for (int fi = 0; fi < 4; fi++) {
            int rb = it * 128 + wi + fi * 16 + lq * 4;
            f32x4 sc = *(const f32x4*)&scale[rb];
            f32x4 sh = *(const f32x4*)&shift[rb];
            #pragma unroll
            for (int fj = 0; fj < 4; fj++) {
                Pack4 pk;
                #pragma unroll
                for (int reg = 0; reg < 4; reg++) {
                    float v = acc[fi][fj][reg] * sc[reg] + sh[reg];
                    if (RELU) v = fmaxf(v, 0.f);
                    pk.u[reg] = f2bf(v);
                }
                *(uint2*)&((u16*)out)[(size_t)jc[fj] * 256 + rb] = pk.v2;
            }
        }
    } else {
        int jcb[4], jcm[4];
        #pragma unroll
        for (int fj = 0; fj < 4; fj++) {
            int jc = jt * 128 + wj + fj * 16 + lr;
            int b = jc / HoWo;
            jcb[fj] = b; jcm[fj] = jc - b * HoWo;
        }
        #pragma unroll
        for (int fi = 0; fi < 4; fi++) {
            int rb = it * 128 + wi + fi * 16 + lq * 4;
            f32x4 sc = *(const f32x4*)&scale[rb];
            f32x4 sh = *(const f32x4*)&shift[rb];
            #pragma unroll
            for (int reg = 0; reg < 4; reg++) {
                int r = rb + reg;
                #pragma unroll
                for (int fj = 0; fj < 4; fj++) {
                    float v = acc[fi][fj][reg] * sc[reg] + sh[reg];
                    if (RELU) v = fmaxf(v, 0.f);
                    size_t o = ((size_t)(jcb[fj] * 256 + r)) * HoWo + jcm[fj];
                    ((float*)out)[o] = v;
                }
            }
        }
    }
}

// ---------------------------------------------------------------------------
// 256x256-tile 8-phase pipelined implicit-im2col GEMM (stage 2).
// 512 threads = 8 waves (2M x 4N), per-wave 128x64 output, BK=64.
// LDS 128 KiB: 2 slots x (A 32KB + B 32KB), XOR-chunk swizzled rows of 128B.
// Per K-tile j: 4 phases = output quadrants; each phase
//   {ds_read new frags || stage 1 half-tile -> s_barrier -> lgkmcnt(0) ->
//    setprio(1) -> 16 MFMA -> setprio(0) -> s_barrier}.
// Stage order during tile j: A(j+1)h1, B(j+1)h1, B(j+2)h0, A(j+2)h0;
// counted s_waitcnt vmcnt(4) once per tile (drain to 0 only at the tail,
// where the j+2 stages are skipped). Same-slot stages are only issued after
// the closing barrier of the last phase that reads that region:
//   A reads done after phase2's closing barrier, B reads after phase1's.
// ---------------------------------------------------------------------------
template<int TAPS>
__global__ __launch_bounds__(512, 2)
void conv_gemm8(const u16* __restrict__ in, const u16* __restrict__ W,
                const float* __restrict__ scale, const float* __restrict__ shift,
                u16* __restrict__ out, int Hi, int Wi, int Ho, int Wo, int npix)
{
    constexpr int KT = TAPS * 256;
    constexpr int NT = KT / 64;           // K-tiles (36 for TAPS=9)
    static_assert(NT >= 2, "pipeline needs >=2 K-tiles");
    const int HoWo = Ho * Wo;

    __shared__ u16 ldsbuf[65536];         // 128 KB

    const int tid  = threadIdx.x;
    const int jt   = blockIdx.x;
    const int wv   = tid >> 6;            // wave 0..7
    const int lane = tid & 63;
    const int wm   = wv >> 2;             // 0..1 : A rows half
    const int wn   = wv & 3;              // 0..3 : B cols quarter
    const int lr   = lane & 15;
    const int lq   = lane >> 4;

    // ---- staging coords: 512 threads cover 64 rows x 8 chunks per q-group
    const int c8  = tid & 7;
    const int rr  = tid >> 3;             // 0..63
    const int csw = (c8 ^ (rr & 7)) * 8;  // swizzled global chunk (u16 units)

    // A rows: oc = h*128 + q*64 + rr
    const u16* gA00 = W + (size_t)(rr)        * KT + csw;
    const u16* gA01 = W + (size_t)(64  + rr)  * KT + csw;
    const u16* gA10 = W + (size_t)(128 + rr)  * KT + csw;
    const u16* gA11 = W + (size_t)(192 + rr)  * KT + csw;

    // B rows: pixel = jt*256 + h*128 + q*64 + rr (clamped)
    const u16* gB00; const u16* gB01; const u16* gB10; const u16* gB11;
    {
        #pragma unroll
        for (int hq = 0; hq < 4; hq++) {
            int jg = jt * 256 + hq * 64 + rr;
            if (jg >= npix) jg = npix - 1;
            int bb  = jg / HoWo;
            int msp = jg - bb * HoWo;
            int oy  = msp / Wo;
            int ox  = msp - oy * Wo;
            const u16* p = in + ((size_t)((bb * Hi + oy) * Wi + ox)) * 256 + csw;
            if (hq == 0) gB00 = p; else if (hq == 1) gB01 = p;
            else if (hq == 2) gB10 = p; else gB11 = p;
        }
    }

    // stage one half-tile (2 x gld_lds16 per thread)
    #define STA(slot_, h_, j_) do { if ((j_) < NT) {                          \
        const int _ao = (j_) * 64;                                            \
        u16* _d = ldsbuf + (slot_) * 32768 + (h_) * 8192 + wv * 512;          \
        gld_lds16(((h_) ? gA10 : gA00) + _ao, _d);                            \
        gld_lds16(((h_) ? gA11 : gA01) + _ao, _d + 4096);                     \
    } } while (0)

    #define STB(slot_, h_, j_) do { if ((j_) < NT) {                          \
        int _ky = 0, _kx = 0;                                                 \
        if (TAPS == 9) { int _t = (j_) >> 2; _ky = _t / 3; _kx = _t - _ky*3; }\
        const int _bo = (_ky * Wi + _kx) * 256 + ((j_) & 3) * 64;             \
        u16* _d = ldsbuf + (slot_) * 32768 + 16384 + (h_) * 8192 + wv * 512;  \
        gld_lds16(((h_) ? gB10 : gB00) + _bo, _d);                            \
        gld_lds16(((h_) ? gB11 : gB01) + _bo, _d + 4096);                     \
    } } while (0)

    #define DSA(RQ) do {                                                      \
        _Pragma("unroll")                                                     \
        for (int ks = 0; ks < 2; ks++) {                                      \
            const int _cx = ks ? x1 : x0;                                     \
            _Pragma("unroll")                                                 \
            for (int f = 0; f < 4; f++) {                                     \
                int _ra = wm * 128 + (RQ) * 64 + f * 16 + lr;                 \
                aF[ks][f] = *(const bf16x8*)&ldsbuf[sA + _ra * 64 + _cx];     \
            }                                                                 \
        }                                                                     \
    } while (0)

    #define DSB(BF, CQ) do {                                                  \
        _Pragma("unroll")                                                     \
        for (int ks = 0; ks < 2; ks++) {                                      \
            const int _cx = ks ? x1 : x0;                                     \
            _Pragma("unroll")                                                 \
            for (int g = 0; g < 2; g++) {                                     \
                int _rb = wn * 64 + (CQ) * 32 + g * 16 + lr;                  \
                BF[ks][g] = *(const bf16x8*)&ldsbuf[sB + _rb * 64 + _cx];     \
            }                                                                 \
        }                                                                     \
    } while (0)

    #define MFMA16(AF, BF, RO, CO) do {                                       \
        __builtin_amdgcn_s_setprio(1);                                        \
        _Pragma("unroll")                                                     \
        for (int ks = 0; ks < 2; ks++)                                        \
            _Pragma("unroll")                                                 \
            for (int f = 0; f < 4; f++)                                       \
                _Pragma("unroll")                                             \
                for (int g = 0; g < 2; g++)                                   \
                    acc[(RO) + f][(CO) + g] =                                 \
                        __builtin_amdgcn_mfma_f32_16x16x32_bf16(              \
                            AF[ks][f], BF[ks][g], acc[(RO) + f][(CO) + g],    \
                            0, 0, 0);                                         \
        __builtin_amdgcn_s_setprio(0);                                        \
    } while (0)

    f32x4 acc[8][4];
    #pragma unroll
    for (int a = 0; a < 8; a++)
        #pragma unroll
        for (int b = 0; b < 4; b++)
            acc[a][b] = (f32x4){0.f, 0.f, 0.f, 0.f};

    const int x0 = ((0 * 4 + lq) ^ (lr & 7)) * 8;   // k-chunk offset, ks=0
    const int x1 = ((1 * 4 + lq) ^ (lr & 7)) * 8;   // k-chunk offset, ks=1

    // ---- prologue: tile0 complete + B(1)h0 + A(1)h0 in flight
    STA(0, 0, 0); STA(0, 1, 0); STB(0, 0, 0); STB(0, 1, 0);
    STB(1, 0, 1); STA(1, 0, 1);
    asm volatile("s_waitcnt vmcnt(4)" ::: "memory");
    __builtin_amdgcn_s_barrier();

    for (int j = 0; j < NT; j++) {
        const int slot = j & 1;
        const int nsl  = slot ^ 1;
        const int sA   = slot * 32768;
        const int sB   = sA + 16384;
        bf16x8 aF[2][4], bF0[2][2], bF1[2][2];

        // ---- phase 0: quadrant (r=0, c=0)
        DSA(0); DSB(bF0, 0);
        STA(nsl, 1, j + 1);
        __builtin_amdgcn_s_barrier();
        asm volatile("s_waitcnt lgkmcnt(0)" ::: "memory");
        MFMA16(aF, bF0, 0, 0);
        __builtin_amdgcn_s_barrier();

        // ---- phase 1: quadrant (r=0, c=1)
        DSB(bF1, 1);
        STB(nsl, 1, j + 1);
        __builtin_amdgcn_s_barrier();
        asm volatile("s_waitcnt lgkmcnt(0)" ::: "memory");
        MFMA16(aF, bF1, 0, 2);
        __builtin_amdgcn_s_barrier();

        // ---- phase 2: quadrant (r=1, c=0)  [all B reads of tile j done]
        DSA(1);
        STB(slot, 0, j + 2);
        __builtin_amdgcn_s_barrier();
        asm volatile("s_waitcnt lgkmcnt(0)" ::: "memory");
        MFMA16(aF, bF0, 4, 0);
        __builtin_amdgcn_s_barrier();

        // ---- phase 3: quadrant (r=1, c=1)  [all A reads of tile j done]
        STA(slot, 0, j + 2);
        if (j + 2 < NT) asm volatile("s_waitcnt vmcnt(4)" ::: "memory");
        else            asm volatile("s_waitcnt vmcnt(0)" ::: "memory");
        __builtin_amdgcn_s_barrier();
        MFMA16(aF, bF1, 4, 2);
        __builtin_amdgcn_s_barrier();
    }

    #undef STA
    #undef STB
    #undef DSA
    #undef DSB
    #undef MFMA16

    // ---- epilogue: BN scale/shift + ReLU, NHWC bf16
    const int obase = jt * 256;
    #pragma unroll
    for (int fr = 0; fr < 8; fr++) {
        const int rb = wm * 128 + fr * 16 + lq * 4;
        const f32x4 sc = *(const f32x4*)&scale[rb];
        const f32x4 sh = *(const f32x4*)&shift[rb];
        #pragma unroll
        for (int fc = 0; fc < 4; fc++) {
            const int jc = obase + wn * 64 + fc * 16 + lr;
            if (jc < npix) {
                Pack4 pk;
                #pragma unroll
                for (int reg = 0; reg < 4; reg++) {
                    float v = acc[fr][fc][reg] * sc[reg] + sh[reg];
                    v = fmaxf(v, 0.f);
                    pk.u[reg] = f2bf(v);
                }
                *(uint2*)&out[(size_t)jc * 256 + rb] = pk.v2;
            }
        }
    }
}

// ---------------------------------------------------------------------------
// Depthwise xcorr, NHWC: feat[b,oy,ox,c] = sum_{5x5} s[b,oy+dy,ox+dx,c]*k[b,dy,dx,c]
// ---------------------------------------------------------------------------
__global__ __launch_bounds__(256)
void xcorr_kernel(const u16* __restrict__ s, const u16* __restrict__ k,
                  u16* __restrict__ out)
{
    const int b = blockIdx.x / 25;
    const int oy = blockIdx.x - b * 25;
    const int c = threadIdx.x;

    float kf[25];
    #pragma unroll
    for (int t = 0; t < 25; t++)
        kf[t] = bf2f(k[((size_t)(b * 25 + t)) * 256 + c]);

    float acc[25];
    #pragma unroll
    for (int i = 0; i < 25; i++) acc[i] = 0.f;

    for (int dy = 0; dy < 5; dy++) {
        float row[29];
        const u16* sp = s + ((size_t)(b * 29 + oy + dy) * 29) * 256 + c;
        #pragma unroll
        for (int x = 0; x < 29; x++) row[x] = bf2f(sp[(size_t)x * 256]);
        #pragma unroll
        for (int dx = 0; dx < 5; dx++) {
            float kv = kf[dy * 5 + dx];
            #pragma unroll
            for (int ox = 0; ox < 25; ox++)
                acc[ox] += row[ox + dx] * kv;
        }
    }
    u16* op = out + ((size_t)(b * 25 + oy) * 25) * 256 + c;
    #pragma unroll
    for (int ox = 0; ox < 25; ox++)
        op[(size_t)ox * 256] = f2bf(acc[ox]);
}

// ---------------------------------------------------------------------------
// Merged weight/BN prep (one launch)
// ---------------------------------------------------------------------------
__global__ __launch_bounds__(256)
void prep_all(const float* __restrict__ wk, const float* __restrict__ wsw,
              const float* __restrict__ wh1, const float* __restrict__ wh2,
              const float* gk, const float* bk, const float* mk, const float* vk,
              const float* gs, const float* bs, const float* ms, const float* vs,
              const float* gh, const float* bh, const float* mh, const float* vh,
              const float* bh2,
              u16* __restrict__ Wk2, u16* __restrict__ Ws2,
              u16* __restrict__ Wh1b, u16* __restrict__ Wh2b,
              float* sk, float* tk, float* ss, float* ts,
              float* sh, float* th, float* s5, float* t5)
{
    int blk = blockIdx.x;
    int tidx = threadIdx.x;
    if (blk < 4608) {
        const float* w = (blk < 2304) ? wk : wsw;
        u16* o = (blk < 2304) ? Wk2 : Ws2;
        int idx = (blk % 2304) * 256 + tidx;
        int oc = idx / 2304, rem = idx - oc * 2304;
        int tap = rem >> 8, c = rem & 255;
        o[idx] = f2bf(w[oc * 2304 + c * 9 + tap]);
    } else if (blk < 5120) {
        const float* w = (blk < 4864) ? wh1 : wh2;
        u16* o = (blk < 4864) ? Wh1b : Wh2b;
        int idx = ((blk - 4608) % 256) * 256 + tidx;
        o[idx] = f2bf(w[idx]);
    } else {
        int i = tidx;
        float iv;
        iv = rsqrtf(vk[i] + EPS_BN) * gk[i]; sk[i] = iv; tk[i] = bk[i] - mk[i] * iv;
        iv = rsqrtf(vs[i] + EPS_BN) * gs[i]; ss[i] = iv; ts[i] = bs[i] - ms[i] * iv;
        iv = rsqrtf(vh[i] + EPS_BN) * gh[i]; sh[i] = iv; th[i] = bh[i] - mh[i] * iv;
        s5[i] = 1.f; t5[i] = bh2[i];
    }
}

// ---------------------------------------------------------------------------
extern "C" void kernel_launch(void* const* d_in, const int* in_sizes, int n_in,
                              void* d_out, int out_size, void* d_ws, size_t ws_size,
                              hipStream_t stream)
{
    const float* in_kernel = (const float*)d_in[0];
    const float* in_search = (const float*)d_in[1];
    const float* wk  = (const float*)d_in[2];
    const float* gk  = (const float*)d_in[3];
    const float* bk  = (const float*)d_in[4];
    const float* mk  = (const float*)d_in[5];
    const float* vk  = (const float*)d_in[6];
    const float* wsw = (const float*)d_in[7];
    const float* gs  = (const float*)d_in[8];
    const float* bs  = (const float*)d_in[9];
    const float* ms  = (const float*)d_in[10];
    const float* vs  = (const float*)d_in[11];
    const float* wh1 = (const float*)d_in[12];
    const float* gh  = (const float*)d_in[13];
    const float* bh  = (const float*)d_in[14];
    const float* mh  = (const float*)d_in[15];
    const float* vh  = (const float*)d_in[16];
    const float* wh2 = (const float*)d_in[17];
    const float* bh2 = (const float*)d_in[18];
    float* out = (float*)d_out;

    char* w = (char*)d_ws;
    u16* Wk2 = (u16*)w;  w += 1179648;      // 256*2304 bf16
    u16* Ws2 = (u16*)w;  w += 1179648;
    u16* Wh1 = (u16*)w;  w += 131072;       // 256*256 bf16
    u16* Wh2 = (u16*)w;  w += 131072;
    float* sk = (float*)w; w += 1024;
    float* tk = (float*)w; w += 1024;
    float* ss = (float*)w; w += 1024;
    float* ts = (float*)w; w += 1024;
    float* sh = (float*)w; w += 1024;
    float* th = (float*)w; w += 1024;
    float* s5 = (float*)w; w += 1024;
    float* t5 = (float*)w; w += 1024;
    u16* kfeat = (u16*)w; w += 1638400;     // 128*25*256 bf16
    u16* sfeat = (u16*)w; w += 55115776;    // 128*841*256 bf16
    u16* feat  = (u16*)w; w += 40960000;    // 128*625*256 bf16
    u16* ktr   = (u16*)w; w += 3211264;     // 128*49*256 bf16 (NHWC kernel input)
    u16* strA  = (u16*)w; w += 62980096;    // 128*961*256 bf16 (NHWC search input)
    u16* hbuf  = strA;                      // alias: strA dead after stage 2

    tr_all<<<481 + 25, 256, 0, stream>>>(in_search, in_kernel, strA, ktr);
    prep_all<<<5121, 256, 0, stream>>>(wk, wsw, wh1, wh2,
                                       gk, bk, mk, vk, gs, bs, ms, vs,
                                       gh, bh, mh, vh, bh2,
                                       Wk2, Ws2, Wh1, Wh2,
                                       sk, tk, ss, ts, sh, th, s5, t5);

    // stage 1: kernel tower  -> kfeat NHWC [128*25, 256]  (old structure)
    conv_gemm<9, true, u16, true><<<dim3(2, 25), 256, 0, stream>>>(
        ktr, Wk2, sk, tk, kfeat, 7, 7, 5, 5);
    // stage 2: search tower  -> sfeat NHWC [128*841, 256]
    //   256x256-tile 8-phase pipeline: 421 J-tiles, full M=256 per block.
    conv_gemm8<9><<<dim3(421), 512, 0, stream>>>(
        strA, Ws2, ss, ts, sfeat, 31, 31, 29, 29, 128 * 841);
    // stage 3: depthwise xcorr -> feat NHWC [128*625, 256]
    xcorr_kernel<<<128 * 25, 256, 0, stream>>>(sfeat, kfeat, feat);
    // stage 4: head 1x1 + BN + ReLU -> hbuf NHWC
    conv_gemm<1, true, u16, true><<<dim3(2, 625), 256, 0, stream>>>(
        feat, Wh1, sh, th, hbuf, 25, 25, 25, 25);
    // stage 5: head 1x1 + bias -> out NCHW fp32
    conv_gemm<1, false, float, false><<<dim3(2, 625), 256, 0, stream>>>(
        hbuf, Wh2, s5, t5, out, 25, 25, 25, 25);

    (void)in_sizes; (void)n_in; (void)out_size; (void)ws_size;
}

// Round 2
// 621.412 us; speedup vs baseline: 1.1305x; 1.0725x over previous
//
#include <hip/hip_runtime.h>
#include <hip/hip_bf16.h>
#include <cstdint>
#include <cstddef>

typedef unsigned short u16;
typedef __attribute__((ext_vector_type(8))) __bf16 bf16x8;
typedef __attribute__((ext_vector_type(4))) float f32x4;

#define EPS_BN 1e-5f

__device__ __forceinline__ u16 f2bf(float f) {
    union { float f; uint32_t u; } v; v.f = f;
    uint32_t u = v.u;
    u += 0x7FFFu + ((u >> 16) & 1u);   // round-to-nearest-even
    return (u16)(u >> 16);
}
__device__ __forceinline__ float bf2f(u16 s) {
    union { uint32_t u; float f; } v; v.u = ((uint32_t)s) << 16;
    return v.f;
}

union Pack8 { u16 u[8]; uint4 v4; };
union Pack4 { u16 u[4]; uint2 v2; };

// async global -> LDS, 16B per lane; LDS dest = wave-uniform base + lane*16
typedef __attribute__((address_space(1))) const unsigned char as1c;
typedef __attribute__((address_space(3))) unsigned char as3;
__device__ __forceinline__ void gld_lds16(const void* g, void* l) {
    __builtin_amdgcn_global_load_lds((as1c*)g, (as3*)l, 16, 0, 0);
}

// ---------------------------------------------------------------------------
// Transpose NCHW fp32 -> NHWC bf16, cache-mediated (no LDS).
// Block = 256 threads; tile = 64 pixels x 256 channels of one batch.
// Thread t: cp = t&31 (8-channel 16B output chunk), pr = t>>5 (pixel row).
// Per iteration: 8 scalar reads strided by P (input 64B lines fully consumed
// by neighboring threads/iterations -> L1/L2 serve the reuse), then ONE
// fully-coalesced uint4 store (32 lanes = contiguous 512B pixel row).
// Grid: 128*16 tiles (search) + 128 tiles (kernel) = 2176 blocks -> high TLP.
// ---------------------------------------------------------------------------
__device__ __forceinline__ void tr_tile(const float* __restrict__ in,
                                        u16* __restrict__ out,
                                        int P, int b, int p0)
{
    const int cp = threadIdx.x & 31;
    const int pr = threadIdx.x >> 5;
    const float* ib = in + (size_t)b * 256 * P + (size_t)cp * 8 * P;
    u16* ob = out + (size_t)(b * P + p0) * 256 + cp * 8;

    #pragma unroll
    for (int it = 0; it < 8; it++) {
        int px = it * 8 + pr;
        int p  = p0 + px;
        bool ok = (p < P);
        int pc = ok ? p : (P - 1);      // clamp: duplicate reads are harmless
        Pack8 pk;
        #pragma unroll
        for (int i = 0; i < 8; i++)
            pk.u[i] = f2bf(ib[(size_t)i * P + pc]);
        if (ok) *(uint4*)(ob + (size_t)px * 256) = pk.v4;
    }
}

__global__ __launch_bounds__(256)
void tr_all(const float* __restrict__ s, const float* __restrict__ k,
            u16* __restrict__ so, u16* __restrict__ ko)
{
    int blk = blockIdx.x;
    if (blk < 2048) {
        // search: 961 pixels -> 16 tiles of 64 per batch
        tr_tile(s, so, 961, blk >> 4, (blk & 15) * 64);
    } else {
        // kernel: 49 pixels -> 1 tile per batch
        tr_tile(k, ko, 49, blk - 2048, 0);
    }
}

// ---------------------------------------------------------------------------
// Implicit-im2col GEMM, NHWC bf16 input (old 128x128 / 4-wave structure).
// Kept for stages 1, 4, 5 (small-N or short-K launches).
// ---------------------------------------------------------------------------
template<int TAPS, bool NHWC_OUT, typename OutT, bool RELU>
__global__ __launch_bounds__(256)
void conv_gemm(const u16* __restrict__ in, const u16* __restrict__ W,
               const float* __restrict__ scale, const float* __restrict__ shift,
               OutT* __restrict__ out, int Hi, int Wi, int Ho, int Wo)
{
    constexpr int KT = TAPS * 256;
    constexpr int KB = KT / 64;
    const int HoWo = Ho * Wo;

    __shared__ u16 Alds[8192];   // 16 KB: [row 0..127][128B swizzled]
    __shared__ u16 Blds[8192];   // 16 KB: [pix 0..127][128B swizzled]

    const int tid = threadIdx.x;
    const int it = blockIdx.x;   // I tile (oc): 0..1
    const int jt = blockIdx.y;   // J tile
    const int wv = tid >> 6;
    const int lane = tid & 63;

    const int c8 = tid & 7;
    const int t3 = tid >> 3;
    const int csw = c8 ^ (t3 & 7);     // swizzled global chunk (row&7 == t3&7)

    const u16* gA[4];
    const u16* gB[4];
    #pragma unroll
    for (int q = 0; q < 4; q++) {
        int r = q * 32 + t3;
        gA[q] = W + (size_t)(it * 128 + r) * KT + csw * 8;
        int jg = jt * 128 + r;
        int bb = jg / HoWo;
        int msp = jg - bb * HoWo;
        int oyp = msp / Wo;
        int oxp = msp - oyp * Wo;
        gB[q] = in + ((size_t)(bb * Hi + oyp) * Wi + oxp) * 256 + csw * 8;
    }

    const int wi = (wv >> 1) * 64;
    const int wj = (wv & 1) * 64;
    const int lr = lane & 15;
    const int lq = lane >> 4;

    f32x4 acc[4][4];
    #pragma unroll
    for (int a = 0; a < 4; a++)
        #pragma unroll
        for (int b = 0; b < 4; b++)
            acc[a][b] = (f32x4){0.f, 0.f, 0.f, 0.f};

    for (int kb = 0; kb < KB; kb++) {
        const int tap = (TAPS == 1) ? 0 : (kb >> 2);
        const int c0  = (TAPS == 1) ? (kb * 64) : ((kb & 3) * 64);
        int ky = 0, kx = 0;
        if (TAPS == 9) { ky = tap / 3; kx = tap - ky * 3; }
        const int aoff = tap * 256 + c0;
        const int boff = (ky * Wi + kx) * 256 + c0;
        __syncthreads();
        #pragma unroll
        for (int q = 0; q < 4; q++)
            gld_lds16(gA[q] + aoff, Alds + q * 2048 + wv * 512);
        #pragma unroll
        for (int q = 0; q < 4; q++)
            gld_lds16(gB[q] + boff, Blds + q * 2048 + wv * 512);
        __syncthreads();
        #pragma unroll
        for (int ks = 0; ks < 2; ks++) {
            bf16x8 af[4], bfr[4];
            const int ck = ks * 4 + lq;
            #pragma unroll
            for (int f = 0; f < 4; f++) {
                int ra = wi + f * 16 + lr;
                af[f]  = *(const bf16x8*)&Alds[ra * 64 + ((ck ^ (ra & 7)) * 8)];
                int rb = wj + f * 16 + lr;
                bfr[f] = *(const bf16x8*)&Blds[rb * 64 + ((ck ^ (rb & 7)) * 8)];
            }
            #pragma unroll
            for (int fi = 0; fi < 4; fi++)
                #pragma unroll
                for (int fj = 0; fj < 4; fj++)
                    acc[fi][fj] = __builtin_amdgcn_mfma_f32_16x16x32_bf16(
                        af[fi], bfr[fj], acc[fi][fj], 0, 0, 0);
        }
    }

    if constexpr (NHWC_OUT) {
        int jc[4];
        #pragma unroll
        for (int fj = 0; fj < 4; fj++) jc[fj] = jt * 128 + wj + fj * 16 + lr;
        #pragma unroll
        for (int fi = 0; fi < 4; fi++) {
            int rb = it * 128 + wi + fi * 16 + lq * 4;
            f32x4 sc = *(const f32x4*)&scale[rb];
            f32x4 sh = *(const f32x4*)&shift[rb];
            #pragma unroll
            for (int fj = 0; fj < 4; fj++) {
                Pack4 pk;
                #pragma unroll
                for (int reg = 0; reg < 4; reg++) {
                    float v = acc[fi][fj][reg] * sc[reg] + sh[reg];
                    if (RELU) v = fmaxf(v, 0.f);
                    pk.u[reg] = f2bf(v);
                }
                *(uint2*)&((u16*)out)[(size_t)jc[fj] * 256 + rb] = pk.v2;
            }
        }
    } else {
        int jcb[4], jcm[4];
        #pragma unroll
        for (int fj = 0; fj < 4; fj++) {
            int jc = jt * 128 + wj + fj * 16 + lr;
            int b = jc / HoWo;
            jcb[fj] = b; jcm[fj] = jc - b * HoWo;
        }
        #pragma unroll
        for (int fi = 0; fi < 4; fi++) {
            int rb = it * 128 + wi + fi * 16 + lq * 4;
            f32x4 sc = *(const f32x4*)&scale[rb];
            f32x4 sh = *(const f32x4*)&shift[rb];
            #pragma unroll
            for (int reg = 0; reg < 4; reg++) {
                int r = rb + reg;
                #pragma unroll
                for (int fj = 0; fj < 4; fj++) {
                    float v = acc[fi][fj][reg] * sc[reg] + sh[reg];
                    if (RELU) v = fmaxf(v, 0.f);
                    size_t o = ((size_t)(jcb[fj] * 256 + r)) * HoWo + jcm[fj];
                    ((float*)out)[o] = v;
                }
            }
        }
    }
}

// ---------------------------------------------------------------------------
// 256x256-tile 8-phase pipelined implicit-im2col GEMM (stage 2).
// 512 threads = 8 waves (2M x 4N), per-wave 128x64 output, BK=64.
// LDS 128 KiB: 2 slots x (A 32KB + B 32KB), XOR-chunk swizzled rows of 128B.
// Per K-tile j: 4 phases = output quadrants; each phase
//   {ds_read new frags || stage 1 half-tile -> s_barrier -> lgkmcnt(0) ->
//    setprio(1) -> 16 MFMA -> setprio(0) -> s_barrier}.
// Stage order during tile j: A(j+1)h1, B(j+1)h1, B(j+2)h0, A(j+2)h0;
// counted s_waitcnt vmcnt(4) once per tile (drain to 0 only at the tail,
// where the j+2 stages are skipped). Same-slot stages are only issued after
// the closing barrier of the last phase that reads that region:
//   A reads done after phase2's closing barrier, B reads after phase1's.
// ---------------------------------------------------------------------------
template<int TAPS>
__global__ __launch_bounds__(512, 2)
void conv_gemm8(const u16* __restrict__ in, const u16* __restrict__ W,
                const float* __restrict__ scale, const float* __restrict__ shift,
                u16* __restrict__ out, int Hi, int Wi, int Ho, int Wo, int npix)
{
    constexpr int KT = TAPS * 256;
    constexpr int NT = KT / 64;           // K-tiles (36 for TAPS=9)
    static_assert(NT >= 2, "pipeline needs >=2 K-tiles");
    const int HoWo = Ho * Wo;

    __shared__ u16 ldsbuf[65536];         // 128 KB

    const int tid  = threadIdx.x;
    const int jt   = blockIdx.x;
    const int wv   = tid >> 6;            // wave 0..7
    const int lane = tid & 63;
    const int wm   = wv >> 2;             // 0..1 : A rows half
    const int wn   = wv & 3;              // 0..3 : B cols quarter
    const int lr   = lane & 15;
    const int lq   = lane >> 4;

    // ---- staging coords: 512 threads cover 64 rows x 8 chunks per q-group
    const int c8  = tid & 7;
    const int rr  = tid >> 3;             // 0..63
    const int csw = (c8 ^ (rr & 7)) * 8;  // swizzled global chunk (u16 units)

    // A rows: oc = h*128 + q*64 + rr
    const u16* gA00 = W + (size_t)(rr)        * KT + csw;
    const u16* gA01 = W + (size_t)(64  + rr)  * KT + csw;
    const u16* gA10 = W + (size_t)(128 + rr)  * KT + csw;
    const u16* gA11 = W + (size_t)(192 + rr)  * KT + csw;

    // B rows: pixel = jt*256 + h*128 + q*64 + rr (clamped)
    const u16* gB00; const u16* gB01; const u16* gB10; const u16* gB11;
    {
        #pragma unroll
        for (int hq = 0; hq < 4; hq++) {
            int jg = jt * 256 + hq * 64 + rr;
            if (jg >= npix) jg = npix - 1;
            int bb  = jg / HoWo;
            int msp = jg - bb * HoWo;
            int oy  = msp / Wo;
            int ox  = msp - oy * Wo;
            const u16* p = in + ((size_t)((bb * Hi + oy) * Wi + ox)) * 256 + csw;
            if (hq == 0) gB00 = p; else if (hq == 1) gB01 = p;
            else if (hq == 2) gB10 = p; else gB11 = p;
        }
    }

    // stage one half-tile (2 x gld_lds16 per thread)
    #define STA(slot_, h_, j_) do { if ((j_) < NT) {                          \
        const int _ao = (j_) * 64;                                            \
        u16* _d = ldsbuf + (slot_) * 32768 + (h_) * 8192 + wv * 512;          \
        gld_lds16(((h_) ? gA10 : gA00) + _ao, _d);                            \
        gld_lds16(((h_) ? gA11 : gA01) + _ao, _d + 4096);                     \
    } } while (0)

    #define STB(slot_, h_, j_) do { if ((j_) < NT) {                          \
        int _ky = 0, _kx = 0;                                                 \
        if (TAPS == 9) { int _t = (j_) >> 2; _ky = _t / 3; _kx = _t - _ky*3; }\
        const int _bo = (_ky * Wi + _kx) * 256 + ((j_) & 3) * 64;             \
        u16* _d = ldsbuf + (slot_) * 32768 + 16384 + (h_) * 8192 + wv * 512;  \
        gld_lds16(((h_) ? gB10 : gB00) + _bo, _d);                            \
        gld_lds16(((h_) ? gB11 : gB01) + _bo, _d + 4096);                     \
    } } while (0)

    #define DSA(RQ) do {                                                      \
        _Pragma("unroll")                                                     \
        for (int ks = 0; ks < 2; ks++) {                                      \
            const int _cx = ks ? x1 : x0;                                     \
            _Pragma("unroll")                                                 \
            for (int f = 0; f < 4; f++) {                                     \
                int _ra = wm * 128 + (RQ) * 64 + f * 16 + lr;                 \
                aF[ks][f] = *(const bf16x8*)&ldsbuf[sA + _ra * 64 + _cx];     \
            }                                                                 \
        }                                                                     \
    } while (0)

    #define DSB(BF, CQ) do {                                                  \
        _Pragma("unroll")                                                     \
        for (int ks = 0; ks < 2; ks++) {                                      \
            const int _cx = ks ? x1 : x0;                                     \
            _Pragma("unroll")                                                 \
            for (int g = 0; g < 2; g++) {                                     \
                int _rb = wn * 64 + (CQ) * 32 + g * 16 + lr;                  \
                BF[ks][g] = *(const bf16x8*)&ldsbuf[sB + _rb * 64 + _cx];     \
            }                                                                 \
        }                                                                     \
    } while (0)

    #define MFMA16(AF, BF, RO, CO) do {                                       \
        __builtin_amdgcn_s_setprio(1);                                        \
        _Pragma("unroll")                                                     \
        for (int ks = 0; ks < 2; ks++)                                        \
            _Pragma("unroll")                                                 \
            for (int f = 0; f < 4; f++)                                       \
                _Pragma("unroll")                                             \
                for (int g = 0; g < 2; g++)                                   \
                    acc[(RO) + f][(CO) + g] =                                 \
                        __builtin_amdgcn_mfma_f32_16x16x32_bf16(              \
                            AF[ks][f], BF[ks][g], acc[(RO) + f][(CO) + g],    \
                            0, 0, 0);                                         \
        __builtin_amdgcn_s_setprio(0);                                        \
    } while (0)

    f32x4 acc[8][4];
    #pragma unroll
    for (int a = 0; a < 8; a++)
        #pragma unroll
        for (int b = 0; b < 4; b++)
            acc[a][b] = (f32x4){0.f, 0.f, 0.f, 0.f};

    const int x0 = ((0 * 4 + lq) ^ (lr & 7)) * 8;   // k-chunk offset, ks=0
    const int x1 = ((1 * 4 + lq) ^ (lr & 7)) * 8;   // k-chunk offset, ks=1

    // ---- prologue: tile0 complete + B(1)h0 + A(1)h0 in flight
    STA(0, 0, 0); STA(0, 1, 0); STB(0, 0, 0); STB(0, 1, 0);
    STB(1, 0, 1); STA(1, 0, 1);
    asm volatile("s_waitcnt vmcnt(4)" ::: "memory");
    __builtin_amdgcn_s_barrier();

    for (int j = 0; j < NT; j++) {
        const int slot = j & 1;
        const int nsl  = slot ^ 1;
        const int sA   = slot * 32768;
        const int sB   = sA + 16384;
        bf16x8 aF[2][4], bF0[2][2], bF1[2][2];

        // ---- phase 0: quadrant (r=0, c=0)
        DSA(0); DSB(bF0, 0);
        STA(nsl, 1, j + 1);
        __builtin_amdgcn_s_barrier();
        asm volatile("s_waitcnt lgkmcnt(0)" ::: "memory");
        MFMA16(aF, bF0, 0, 0);
        __builtin_amdgcn_s_barrier();

        // ---- phase 1: quadrant (r=0, c=1)
        DSB(bF1, 1);
        STB(nsl, 1, j + 1);
        __builtin_amdgcn_s_barrier();
        asm volatile("s_waitcnt lgkmcnt(0)" ::: "memory");
        MFMA16(aF, bF1, 0, 2);
        __builtin_amdgcn_s_barrier();

        // ---- phase 2: quadrant (r=1, c=0)  [all B reads of tile j done]
        DSA(1);
        STB(slot, 0, j + 2);
        __builtin_amdgcn_s_barrier();
        asm volatile("s_waitcnt lgkmcnt(0)" ::: "memory");
        MFMA16(aF, bF0, 4, 0);
        __builtin_amdgcn_s_barrier();

        // ---- phase 3: quadrant (r=1, c=1)  [all A reads of tile j done]
        STA(slot, 0, j + 2);
        if (j + 2 < NT) asm volatile("s_waitcnt vmcnt(4)" ::: "memory");
        else            asm volatile("s_waitcnt vmcnt(0)" ::: "memory");
        __builtin_amdgcn_s_barrier();
        MFMA16(aF, bF1, 4, 2);
        __builtin_amdgcn_s_barrier();
    }

    #undef STA
    #undef STB
    #undef DSA
    #undef DSB
    #undef MFMA16

    // ---- epilogue: BN scale/shift + ReLU, NHWC bf16
    const int obase = jt * 256;
    #pragma unroll
    for (int fr = 0; fr < 8; fr++) {
        const int rb = wm * 128 + fr * 16 + lq * 4;
        const f32x4 sc = *(const f32x4*)&scale[rb];
        const f32x4 sh = *(const f32x4*)&shift[rb];
        #pragma unroll
        for (int fc = 0; fc < 4; fc++) {
            const int jc = obase + wn * 64 + fc * 16 + lr;
            if (jc < npix) {
                Pack4 pk;
                #pragma unroll
                for (int reg = 0; reg < 4; reg++) {
                    float v = acc[fr][fc][reg] * sc[reg] + sh[reg];
                    v = fmaxf(v, 0.f);
                    pk.u[reg] = f2bf(v);
                }
                *(uint2*)&out[(size_t)jc * 256 + rb] = pk.v2;
            }
        }
    }
}

// ---------------------------------------------------------------------------
// Depthwise xcorr, NHWC: feat[b,oy,ox,c] = sum_{5x5} s[b,oy+dy,ox+dx,c]*k[b,dy,dx,c]
// ---------------------------------------------------------------------------
__global__ __launch_bounds__(256)
void xcorr_kernel(const u16* __restrict__ s, const u16* __restrict__ k,
                  u16* __restrict__ out)
{
    const int b = blockIdx.x / 25;
    const int oy = blockIdx.x - b * 25;
    const int c = threadIdx.x;

    float kf[25];
    #pragma unroll
    for (int t = 0; t < 25; t++)
        kf[t] = bf2f(k[((size_t)(b * 25 + t)) * 256 + c]);

    float acc[25];
    #pragma unroll
    for (int i = 0; i < 25; i++) acc[i] = 0.f;

    for (int dy = 0; dy < 5; dy++) {
        float row[29];
        const u16* sp = s + ((size_t)(b * 29 + oy + dy) * 29) * 256 + c;
        #pragma unroll
        for (int x = 0; x < 29; x++) row[x] = bf2f(sp[(size_t)x * 256]);
        #pragma unroll
        for (int dx = 0; dx < 5; dx++) {
            float kv = kf[dy * 5 + dx];
            #pragma unroll
            for (int ox = 0; ox < 25; ox++)
                acc[ox] += row[ox + dx] * kv;
        }
    }
    u16* op = out + ((size_t)(b * 25 + oy) * 25) * 256 + c;
    #pragma unroll
    for (int ox = 0; ox < 25; ox++)
        op[(size_t)ox * 256] = f2bf(acc[ox]);
}

// ---------------------------------------------------------------------------
// Merged weight/BN prep (one launch)
// ---------------------------------------------------------------------------
__global__ __launch_bounds__(256)
void prep_all(const float* __restrict__ wk, const float* __restrict__ wsw,
              const float* __restrict__ wh1, const float* __restrict__ wh2,
              const float* gk, const float* bk, const float* mk, const float* vk,
              const float* gs, const float* bs, const float* ms, const float* vs,
              const float* gh, const float* bh, const float* mh, const float* vh,
              const float* bh2,
              u16* __restrict__ Wk2, u16* __restrict__ Ws2,
              u16* __restrict__ Wh1b, u16* __restrict__ Wh2b,
              float* sk, float* tk, float* ss, float* ts,
              float* sh, float* th, float* s5, float* t5)
{
    int blk = blockIdx.x;
    int tidx = threadIdx.x;
    if (blk < 4608) {
        const float* w = (blk < 2304) ? wk : wsw;
        u16* o = (blk < 2304) ? Wk2 : Ws2;
        int idx = (blk % 2304) * 256 + tidx;
        int oc = idx / 2304, rem = idx - oc * 2304;
        int tap = rem >> 8, c = rem & 255;
        o[idx] = f2bf(w[oc * 2304 + c * 9 + tap]);
    } else if (blk < 5120) {
        const float* w = (blk < 4864) ? wh1 : wh2;
        u16* o = (blk < 4864) ? Wh1b : Wh2b;
        int idx = ((blk - 4608) % 256) * 256 + tidx;
        o[idx] = f2bf(w[idx]);
    } else {
        int i = tidx;
        float iv;
        iv = rsqrtf(vk[i] + EPS_BN) * gk[i]; sk[i] = iv; tk[i] = bk[i] - mk[i] * iv;
        iv = rsqrtf(vs[i] + EPS_BN) * gs[i]; ss[i] = iv; ts[i] = bs[i] - ms[i] * iv;
        iv = rsqrtf(vh[i] + EPS_BN) * gh[i]; sh[i] = iv; th[i] = bh[i] - mh[i] * iv;
        s5[i] = 1.f; t5[i] = bh2[i];
    }
}

// ---------------------------------------------------------------------------
extern "C" void kernel_launch(void* const* d_in, const int* in_sizes, int n_in,
                              void* d_out, int out_size, void* d_ws, size_t ws_size,
                              hipStream_t stream)
{
    const float* in_kernel = (const float*)d_in[0];
    const float* in_search = (const float*)d_in[1];
    const float* wk  = (const float*)d_in[2];
    const float* gk  = (const float*)d_in[3];
    const float* bk  = (const float*)d_in[4];
    const float* mk  = (const float*)d_in[5];
    const float* vk  = (const float*)d_in[6];
    const float* wsw = (const float*)d_in[7];
    const float* gs  = (const float*)d_in[8];
    const float* bs  = (const float*)d_in[9];
    const float* ms  = (const float*)d_in[10];
    const float* vs  = (const float*)d_in[11];
    const float* wh1 = (const float*)d_in[12];
    const float* gh  = (const float*)d_in[13];
    const float* bh  = (const float*)d_in[14];
    const float* mh  = (const float*)d_in[15];
    const float* vh  = (const float*)d_in[16];
    const float* wh2 = (const float*)d_in[17];
    const float* bh2 = (const float*)d_in[18];
    float* out = (float*)d_out;

    char* w = (char*)d_ws;
    u16* Wk2 = (u16*)w;  w += 1179648;      // 256*2304 bf16
    u16* Ws2 = (u16*)w;  w += 1179648;
    u16* Wh1 = (u16*)w;  w += 131072;       // 256*256 bf16
    u16* Wh2 = (u16*)w;  w += 131072;
    float* sk = (float*)w; w += 1024;
    float* tk = (float*)w; w += 1024;
    float* ss = (float*)w; w += 1024;
    float* ts = (float*)w; w += 1024;
    float* sh = (float*)w; w += 1024;
    float* th = (float*)w; w += 1024;
    float* s5 = (float*)w; w += 1024;
    float* t5 = (float*)w; w += 1024;
    u16* kfeat = (u16*)w; w += 1638400;     // 128*25*256 bf16
    u16* sfeat = (u16*)w; w += 55115776;    // 128*841*256 bf16
    u16* feat  = (u16*)w; w += 40960000;    // 128*625*256 bf16
    u16* ktr   = (u16*)w; w += 3211264;     // 128*49*256 bf16 (NHWC kernel input)
    u16* strA  = (u16*)w; w += 62980096;    // 128*961*256 bf16 (NHWC search input)
    u16* hbuf  = strA;                      // alias: strA dead after stage 2

    tr_all<<<2048 + 128, 256, 0, stream>>>(in_search, in_kernel, strA, ktr);
    prep_all<<<5121, 256, 0, stream>>>(wk, wsw, wh1, wh2,
                                       gk, bk, mk, vk, gs, bs, ms, vs,
                                       gh, bh, mh, vh, bh2,
                                       Wk2, Ws2, Wh1, Wh2,
                                       sk, tk, ss, ts, sh, th, s5, t5);

    // stage 1: kernel tower  -> kfeat NHWC [128*25, 256]  (old structure)
    conv_gemm<9, true, u16, true><<<dim3(2, 25), 256, 0, stream>>>(
        ktr, Wk2, sk, tk, kfeat, 7, 7, 5, 5);
    // stage 2: search tower  -> sfeat NHWC [128*841, 256]
    //   256x256-tile 8-phase pipeline: 421 J-tiles, full M=256 per block.
    conv_gemm8<9><<<dim3(421), 512, 0, stream>>>(
        strA, Ws2, ss, ts, sfeat, 31, 31, 29, 29, 128 * 841);
    // stage 3: depthwise xcorr -> feat NHWC [128*625, 256]
    xcorr_kernel<<<128 * 25, 256, 0, stream>>>(sfeat, kfeat, feat);
    // stage 4: head 1x1 + BN + ReLU -> hbuf NHWC
    conv_gemm<1, true, u16, true><<<dim3(2, 625), 256, 0, stream>>>(
        feat, Wh1, sh, th, hbuf, 25, 25, 25, 25);
    // stage 5: head 1x1 + bias -> out NCHW fp32
    conv_gemm<1, false, float, false><<<dim3(2, 625), 256, 0, stream>>>(
        hbuf, Wh2, s5, t5, out, 25, 25, 25, 25);

    (void)in_sizes; (void)n_in; (void)out_size; (void)ws_size;
}

// Round 3
// 549.720 us; speedup vs baseline: 1.2780x; 1.1304x over previous
//
#include <hip/hip_runtime.h>
#include <hip/hip_bf16.h>
#include <cstdint>
#include <cstddef>

typedef unsigned short u16;
typedef __attribute__((ext_vector_type(8))) __bf16 bf16x8;
typedef __attribute__((ext_vector_type(4))) float f32x4;

#define EPS_BN 1e-5f

__device__ __forceinline__ u16 f2bf(float f) {
    union { float f; uint32_t u; } v; v.f = f;
    uint32_t u = v.u;
    u += 0x7FFFu + ((u >> 16) & 1u);   // round-to-nearest-even
    return (u16)(u >> 16);
}
__device__ __forceinline__ float bf2f(u16 s) {
    union { uint32_t u; float f; } v; v.u = ((uint32_t)s) << 16;
    return v.f;
}

union Pack8 { u16 u[8]; uint4 v4; };
union Pack4 { u16 u[4]; uint2 v2; };

// async global -> LDS, 16B per lane; LDS dest = wave-uniform base + lane*16
typedef __attribute__((address_space(1))) const unsigned char as1c;
typedef __attribute__((address_space(3))) unsigned char as3;
__device__ __forceinline__ void gld_lds16(const void* g, void* l) {
    __builtin_amdgcn_global_load_lds((as1c*)g, (as3*)l, 16, 0, 0);
}

// ---------------------------------------------------------------------------
// Transpose NCHW fp32 -> NHWC bf16, transaction-optimal register transpose.
// Block = 256 threads = 4 waves; tile = 64 pixels x 256 channels of batch b.
// Wave w handles channels w*64..w*64+63; lane = pixel p0+ln.
// Read: 64 instrs/wave, each = 64 consecutive fp32 of ONE channel row
//   (perfectly coalesced, each 64B input line touched once).
// Thread accumulates its pixel's 64-channel column in registers, then
// stores 8 x uint4 (channels w*64..+63 of out[p]) -- the 4 chunks of each
// 64B output line come from 2 adjacent instrs of the same wave (L2 merges).
// ---------------------------------------------------------------------------
__device__ __forceinline__ void tr_tile(const float* __restrict__ in,
                                        u16* __restrict__ out,
                                        int P, int b, int p0)
{
    const int w  = threadIdx.x >> 6;       // wave: channel block w*64
    const int ln = threadIdx.x & 63;       // lane: pixel p0+ln
    const int p  = p0 + ln;
    const bool ok = (p < P);
    const int pc = ok ? p : (P - 1);       // clamp (in-bounds, store skipped)
    const float* ib = in + ((size_t)b * 256 + w * 64) * P + pc;

    float v[64];
    #pragma unroll
    for (int i = 0; i < 64; i++)
        v[i] = ib[(size_t)i * P];

    if (ok) {
        u16* ob = out + ((size_t)(b * P + p)) * 256 + w * 64;
        #pragma unroll
        for (int k = 0; k < 8; k++) {
            Pack8 pk;
            #pragma unroll
            for (int i = 0; i < 8; i++)
                pk.u[i] = f2bf(v[k * 8 + i]);
            *(uint4*)(ob + k * 8) = pk.v4;
        }
    }
}

__global__ __launch_bounds__(256)
void tr_all(const float* __restrict__ s, const float* __restrict__ k,
            u16* __restrict__ so, u16* __restrict__ ko)
{
    int blk = blockIdx.x;
    if (blk < 2048) {
        // search: 961 pixels -> 16 tiles of 64 per batch
        tr_tile(s, so, 961, blk >> 4, (blk & 15) * 64);
    } else {
        // kernel: 49 pixels -> 1 tile per batch
        tr_tile(k, ko, 49, blk - 2048, 0);
    }
}

// ---------------------------------------------------------------------------
// Implicit-im2col GEMM, NHWC bf16 input (old 128x128 / 4-wave structure).
// Kept for stages 1, 4, 5 (small-N or short-K launches).
// ---------------------------------------------------------------------------
template<int TAPS, bool NHWC_OUT, typename OutT, bool RELU>
__global__ __launch_bounds__(256)
void conv_gemm(const u16* __restrict__ in, const u16* __restrict__ W,
               const float* __restrict__ scale, const float* __restrict__ shift,
               OutT* __restrict__ out, int Hi, int Wi, int Ho, int Wo)
{
    constexpr int KT = TAPS * 256;
    constexpr int KB = KT / 64;
    const int HoWo = Ho * Wo;

    __shared__ u16 Alds[8192];   // 16 KB: [row 0..127][128B swizzled]
    __shared__ u16 Blds[8192];   // 16 KB: [pix 0..127][128B swizzled]

    const int tid = threadIdx.x;
    const int it = blockIdx.x;   // I tile (oc): 0..1
    const int jt = blockIdx.y;   // J tile
    const int wv = tid >> 6;
    const int lane = tid & 63;

    const int c8 = tid & 7;
    const int t3 = tid >> 3;
    const int csw = c8 ^ (t3 & 7);     // swizzled global chunk (row&7 == t3&7)

    const u16* gA[4];
    const u16* gB[4];
    #pragma unroll
    for (int q = 0; q < 4; q++) {
        int r = q * 32 + t3;
        gA[q] = W + (size_t)(it * 128 + r) * KT + csw * 8;
        int jg = jt * 128 + r;
        int bb = jg / HoWo;
        int msp = jg - bb * HoWo;
        int oyp = msp / Wo;
        int oxp = msp - oyp * Wo;
        gB[q] = in + ((size_t)(bb * Hi + oyp) * Wi + oxp) * 256 + csw * 8;
    }

    const int wi = (wv >> 1) * 64;
    const int wj = (wv & 1) * 64;
    const int lr = lane & 15;
    const int lq = lane >> 4;

    f32x4 acc[4][4];
    #pragma unroll
    for (int a = 0; a < 4; a++)
        #pragma unroll
        for (int b = 0; b < 4; b++)
            acc[a][b] = (f32x4){0.f, 0.f, 0.f, 0.f};

    for (int kb = 0; kb < KB; kb++) {
        const int tap = (TAPS == 1) ? 0 : (kb >> 2);
        const int c0  = (TAPS == 1) ? (kb * 64) : ((kb & 3) * 64);
        int ky = 0, kx = 0;
        if (TAPS == 9) { ky = tap / 3; kx = tap - ky * 3; }
        const int aoff = tap * 256 + c0;
        const int boff = (ky * Wi + kx) * 256 + c0;
        __syncthreads();
        #pragma unroll
        for (int q = 0; q < 4; q++)
            gld_lds16(gA[q] + aoff, Alds + q * 2048 + wv * 512);
        #pragma unroll
        for (int q = 0; q < 4; q++)
            gld_lds16(gB[q] + boff, Blds + q * 2048 + wv * 512);
        __syncthreads();
        #pragma unroll
        for (int ks = 0; ks < 2; ks++) {
            bf16x8 af[4], bfr[4];
            const int ck = ks * 4 + lq;
            #pragma unroll
            for (int f = 0; f < 4; f++) {
                int ra = wi + f * 16 + lr;
                af[f]  = *(const bf16x8*)&Alds[ra * 64 + ((ck ^ (ra & 7)) * 8)];
                int rb = wj + f * 16 + lr;
                bfr[f] = *(const bf16x8*)&Blds[rb * 64 + ((ck ^ (rb & 7)) * 8)];
            }
            #pragma unroll
            for (int fi = 0; fi < 4; fi++)
                #pragma unroll
                for (int fj = 0; fj < 4; fj++)
                    acc[fi][fj] = __builtin_amdgcn_mfma_f32_16x16x32_bf16(
                        af[fi], bfr[fj], acc[fi][fj], 0, 0, 0);
        }
    }

    if constexpr (NHWC_OUT) {
        int jc[4];
        #pragma unroll
        for (int fj = 0; fj < 4; fj++) jc[fj] = jt * 128 + wj + fj * 16 + lr;
        #pragma unroll
        for (int fi = 0; fi < 4; fi++) {
            int rb = it * 128 + wi + fi * 16 + lq * 4;
            f32x4 sc = *(const f32x4*)&scale[rb];
            f32x4 sh = *(const f32x4*)&shift[rb];
            #pragma unroll
            for (int fj = 0; fj < 4; fj++) {
                Pack4 pk;
                #pragma unroll
                for (int reg = 0; reg < 4; reg++) {
                    float v = acc[fi][fj][reg] * sc[reg] + sh[reg];
                    if (RELU) v = fmaxf(v, 0.f);
                    pk.u[reg] = f2bf(v);
                }
                *(uint2*)&((u16*)out)[(size_t)jc[fj] * 256 + rb] = pk.v2;
            }
        }
    } else {
        int jcb[4], jcm[4];
        #pragma unroll
        for (int fj = 0; fj < 4; fj++) {
            int jc = jt * 128 + wj + fj * 16 + lr;
            int b = jc / HoWo;
            jcb[fj] = b; jcm[fj] = jc - b * HoWo;
        }
        #pragma unroll
        for (int fi = 0; fi < 4; fi++) {
            int rb = it * 128 + wi + fi * 16 + lq * 4;
            f32x4 sc = *(const f32x4*)&scale[rb];
            f32x4 sh = *(const f32x4*)&shift[rb];
            #pragma unroll
            for (int reg = 0; reg < 4; reg++) {
                int r = rb + reg;
                #pragma unroll
                for (int fj = 0; fj < 4; fj++) {
                    float v = acc[fi][fj][reg] * sc[reg] + sh[reg];
                    if (RELU) v = fmaxf(v, 0.f);
                    size_t o = ((size_t)(jcb[fj] * 256 + r)) * HoWo + jcm[fj];
                    ((float*)out)[o] = v;
                }
            }
        }
    }
}

// ---------------------------------------------------------------------------
// 256x256-tile 8-phase pipelined implicit-im2col GEMM (stage 2).
// 512 threads = 8 waves (2M x 4N), per-wave 128x64 output, BK=64.
// LDS 128 KiB: 2 slots x (A 32KB + B 32KB), XOR-chunk swizzled rows of 128B.
// Per K-tile j: 4 phases = output quadrants; each phase
//   {ds_read new frags || stage 1 half-tile -> s_barrier -> lgkmcnt(0) ->
//    setprio(1) -> 16 MFMA -> setprio(0) -> s_barrier}.
// Stage order during tile j: A(j+1)h1, B(j+1)h1, B(j+2)h0, A(j+2)h0;
// counted s_waitcnt vmcnt(4) once per tile (drain to 0 only at the tail).
// jt is XCD-swizzled (bijective, m204) so neighboring pixel tiles share an
// XCD L2 -> tap-window re-reads hit L2 instead of HBM.
// ---------------------------------------------------------------------------
template<int TAPS>
__global__ __launch_bounds__(512, 2)
void conv_gemm8(const u16* __restrict__ in, const u16* __restrict__ W,
                const float* __restrict__ scale, const float* __restrict__ shift,
                u16* __restrict__ out, int Hi, int Wi, int Ho, int Wo, int npix)
{
    constexpr int KT = TAPS * 256;
    constexpr int NT = KT / 64;           // K-tiles (36 for TAPS=9)
    static_assert(NT >= 2, "pipeline needs >=2 K-tiles");
    const int HoWo = Ho * Wo;

    __shared__ u16 ldsbuf[65536];         // 128 KB

    const int tid  = threadIdx.x;
    // ---- bijective XCD-aware block swizzle (nwg = 421 = 8*52+5)
    const int jt0  = blockIdx.x;
    const int nwg  = gridDim.x;
    const int q8   = nwg >> 3, r8 = nwg & 7;
    const int xcd  = jt0 & 7, sidx = jt0 >> 3;
    const int jt   = (xcd < r8 ? xcd * (q8 + 1)
                               : r8 * (q8 + 1) + (xcd - r8) * q8) + sidx;
    const int wv   = tid >> 6;            // wave 0..7
    const int lane = tid & 63;
    const int wm   = wv >> 2;             // 0..1 : A rows half
    const int wn   = wv & 3;              // 0..3 : B cols quarter
    const int lr   = lane & 15;
    const int lq   = lane >> 4;

    // ---- staging coords: 512 threads cover 64 rows x 8 chunks per q-group
    const int c8  = tid & 7;
    const int rr  = tid >> 3;             // 0..63
    const int csw = (c8 ^ (rr & 7)) * 8;  // swizzled global chunk (u16 units)

    // A rows: oc = h*128 + q*64 + rr
    const u16* gA00 = W + (size_t)(rr)        * KT + csw;
    const u16* gA01 = W + (size_t)(64  + rr)  * KT + csw;
    const u16* gA10 = W + (size_t)(128 + rr)  * KT + csw;
    const u16* gA11 = W + (size_t)(192 + rr)  * KT + csw;

    // B rows: pixel = jt*256 + h*128 + q*64 + rr (clamped)
    const u16* gB00; const u16* gB01; const u16* gB10; const u16* gB11;
    {
        #pragma unroll
        for (int hq = 0; hq < 4; hq++) {
            int jg = jt * 256 + hq * 64 + rr;
            if (jg >= npix) jg = npix - 1;
            int bb  = jg / HoWo;
            int msp = jg - bb * HoWo;
            int oy  = msp / Wo;
            int ox  = msp - oy * Wo;
            const u16* p = in + ((size_t)((bb * Hi + oy) * Wi + ox)) * 256 + csw;
            if (hq == 0) gB00 = p; else if (hq == 1) gB01 = p;
            else if (hq == 2) gB10 = p; else gB11 = p;
        }
    }

    // stage one half-tile (2 x gld_lds16 per thread)
    #define STA(slot_, h_, j_) do { if ((j_) < NT) {                          \
        const int _ao = (j_) * 64;                                            \
        u16* _d = ldsbuf + (slot_) * 32768 + (h_) * 8192 + wv * 512;          \
        gld_lds16(((h_) ? gA10 : gA00) + _ao, _d);                            \
        gld_lds16(((h_) ? gA11 : gA01) + _ao, _d + 4096);                     \
    } } while (0)

    #define STB(slot_, h_, j_) do { if ((j_) < NT) {                          \
        int _ky = 0, _kx = 0;                                                 \
        if (TAPS == 9) { int _t = (j_) >> 2; _ky = _t / 3; _kx = _t - _ky*3; }\
        const int _bo = (_ky * Wi + _kx) * 256 + ((j_) & 3) * 64;             \
        u16* _d = ldsbuf + (slot_) * 32768 + 16384 + (h_) * 8192 + wv * 512;  \
        gld_lds16(((h_) ? gB10 : gB00) + _bo, _d);                            \
        gld_lds16(((h_) ? gB11 : gB01) + _bo, _d + 4096);                     \
    } } while (0)

    #define DSA(RQ) do {                                                      \
        _Pragma("unroll")                                                     \
        for (int ks = 0; ks < 2; ks++) {                                      \
            const int _cx = ks ? x1 : x0;                                     \
            _Pragma("unroll")                                                 \
            for (int f = 0; f < 4; f++) {                                     \
                int _ra = wm * 128 + (RQ) * 64 + f * 16 + lr;                 \
                aF[ks][f] = *(const bf16x8*)&ldsbuf[sA + _ra * 64 + _cx];     \
            }                                                                 \
        }                                                                     \
    } while (0)

    #define DSB(BF, CQ) do {                                                  \
        _Pragma("unroll")                                                     \
        for (int ks = 0; ks < 2; ks++) {                                      \
            const int _cx = ks ? x1 : x0;                                     \
            _Pragma("unroll")                                                 \
            for (int g = 0; g < 2; g++) {                                     \
                int _rb = wn * 64 + (CQ) * 32 + g * 16 + lr;                  \
                BF[ks][g] = *(const bf16x8*)&ldsbuf[sB + _rb * 64 + _cx];     \
            }                                                                 \
        }                                                                     \
    } while (0)

    #define MFMA16(AF, BF, RO, CO) do {                                       \
        __builtin_amdgcn_s_setprio(1);                                        \
        _Pragma("unroll")                                                     \
        for (int ks = 0; ks < 2; ks++)                                        \
            _Pragma("unroll")                                                 \
            for (int f = 0; f < 4; f++)                                       \
                _Pragma("unroll")                                             \
                for (int g = 0; g < 2; g++)                                   \
                    acc[(RO) + f][(CO) + g] =                                 \
                        __builtin_amdgcn_mfma_f32_16x16x32_bf16(              \
                            AF[ks][f], BF[ks][g], acc[(RO) + f][(CO) + g],    \
                            0, 0, 0);                                         \
        __builtin_amdgcn_s_setprio(0);                                        \
    } while (0)

    f32x4 acc[8][4];
    #pragma unroll
    for (int a = 0; a < 8; a++)
        #pragma unroll
        for (int b = 0; b < 4; b++)
            acc[a][b] = (f32x4){0.f, 0.f, 0.f, 0.f};

    const int x0 = ((0 * 4 + lq) ^ (lr & 7)) * 8;   // k-chunk offset, ks=0
    const int x1 = ((1 * 4 + lq) ^ (lr & 7)) * 8;   // k-chunk offset, ks=1

    // ---- prologue: tile0 complete + B(1)h0 + A(1)h0 in flight
    STA(0, 0, 0); STA(0, 1, 0); STB(0, 0, 0); STB(0, 1, 0);
    STB(1, 0, 1); STA(1, 0, 1);
    asm volatile("s_waitcnt vmcnt(4)" ::: "memory");
    __builtin_amdgcn_s_barrier();

    for (int j = 0; j < NT; j++) {
        const int slot = j & 1;
        const int nsl  = slot ^ 1;
        const int sA   = slot * 32768;
        const int sB   = sA + 16384;
        bf16x8 aF[2][4], bF0[2][2], bF1[2][2];

        // ---- phase 0: quadrant (r=0, c=0)
        DSA(0); DSB(bF0, 0);
        STA(nsl, 1, j + 1);
        __builtin_amdgcn_s_barrier();
        asm volatile("s_waitcnt lgkmcnt(0)" ::: "memory");
        MFMA16(aF, bF0, 0, 0);
        __builtin_amdgcn_s_barrier();

        // ---- phase 1: quadrant (r=0, c=1)
        DSB(bF1, 1);
        STB(nsl, 1, j + 1);
        __builtin_amdgcn_s_barrier();
        asm volatile("s_waitcnt lgkmcnt(0)" ::: "memory");
        MFMA16(aF, bF1, 0, 2);
        __builtin_amdgcn_s_barrier();

        // ---- phase 2: quadrant (r=1, c=0)  [all B reads of tile j done]
        DSA(1);
        STB(slot, 0, j + 2);
        __builtin_amdgcn_s_barrier();
        asm volatile("s_waitcnt lgkmcnt(0)" ::: "memory");
        MFMA16(aF, bF0, 4, 0);
        __builtin_amdgcn_s_barrier();

        // ---- phase 3: quadrant (r=1, c=1)  [all A reads of tile j done]
        STA(slot, 0, j + 2);
        if (j + 2 < NT) asm volatile("s_waitcnt vmcnt(4)" ::: "memory");
        else            asm volatile("s_waitcnt vmcnt(0)" ::: "memory");
        __builtin_amdgcn_s_barrier();
        MFMA16(aF, bF1, 4, 2);
        __builtin_amdgcn_s_barrier();
    }

    #undef STA
    #undef STB
    #undef DSA
    #undef DSB
    #undef MFMA16

    // ---- epilogue: BN scale/shift + ReLU, NHWC bf16
    const int obase = jt * 256;
    #pragma unroll
    for (int fr = 0; fr < 8; fr++) {
        const int rb = wm * 128 + fr * 16 + lq * 4;
        const f32x4 sc = *(const f32x4*)&scale[rb];
        const f32x4 sh = *(const f32x4*)&shift[rb];
        #pragma unroll
        for (int fc = 0; fc < 4; fc++) {
            const int jc = obase + wn * 64 + fc * 16 + lr;
            if (jc < npix) {
                Pack4 pk;
                #pragma unroll
                for (int reg = 0; reg < 4; reg++) {
                    float v = acc[fr][fc][reg] * sc[reg] + sh[reg];
                    v = fmaxf(v, 0.f);
                    pk.u[reg] = f2bf(v);
                }
                *(uint2*)&out[(size_t)jc * 256 + rb] = pk.v2;
            }
        }
    }
}

// ---------------------------------------------------------------------------
// Depthwise xcorr, NHWC: feat[b,oy,ox,c] = sum_{5x5} s[b,oy+dy,ox+dx,c]*k[b,dy,dx,c]
// ---------------------------------------------------------------------------
__global__ __launch_bounds__(256)
void xcorr_kernel(const u16* __restrict__ s, const u16* __restrict__ k,
                  u16* __restrict__ out)
{
    const int b = blockIdx.x / 25;
    const int oy = blockIdx.x - b * 25;
    const int c = threadIdx.x;

    float kf[25];
    #pragma unroll
    for (int t = 0; t < 25; t++)
        kf[t] = bf2f(k[((size_t)(b * 25 + t)) * 256 + c]);

    float acc[25];
    #pragma unroll
    for (int i = 0; i < 25; i++) acc[i] = 0.f;

    for (int dy = 0; dy < 5; dy++) {
        float row[29];
        const u16* sp = s + ((size_t)(b * 29 + oy + dy) * 29) * 256 + c;
        #pragma unroll
        for (int x = 0; x < 29; x++) row[x] = bf2f(sp[(size_t)x * 256]);
        #pragma unroll
        for (int dx = 0; dx < 5; dx++) {
            float kv = kf[dy * 5 + dx];
            #pragma unroll
            for (int ox = 0; ox < 25; ox++)
                acc[ox] += row[ox + dx] * kv;
        }
    }
    u16* op = out + ((size_t)(b * 25 + oy) * 25) * 256 + c;
    #pragma unroll
    for (int ox = 0; ox < 25; ox++)
        op[(size_t)ox * 256] = f2bf(acc[ox]);
}

// ---------------------------------------------------------------------------
// Merged weight/BN prep (one launch)
// ---------------------------------------------------------------------------
__global__ __launch_bounds__(256)
void prep_all(const float* __restrict__ wk, const float* __restrict__ wsw,
              const float* __restrict__ wh1, const float* __restrict__ wh2,
              const float* gk, const float* bk, const float* mk, const float* vk,
              const float* gs, const float* bs, const float* ms, const float* vs,
              const float* gh, const float* bh, const float* mh, const float* vh,
              const float* bh2,
              u16* __restrict__ Wk2, u16* __restrict__ Ws2,
              u16* __restrict__ Wh1b, u16* __restrict__ Wh2b,
              float* sk, float* tk, float* ss, float* ts,
              float* sh, float* th, float* s5, float* t5)
{
    int blk = blockIdx.x;
    int tidx = threadIdx.x;
    if (blk < 4608) {
        const float* w = (blk < 2304) ? wk : wsw;
        u16* o = (blk < 2304) ? Wk2 : Ws2;
        int idx = (blk % 2304) * 256 + tidx;
        int oc = idx / 2304, rem = idx - oc * 2304;
        int tap = rem >> 8, c = rem & 255;
        o[idx] = f2bf(w[oc * 2304 + c * 9 + tap]);
    } else if (blk < 5120) {
        const float* w = (blk < 4864) ? wh1 : wh2;
        u16* o = (blk < 4864) ? Wh1b : Wh2b;
        int idx = ((blk - 4608) % 256) * 256 + tidx;
        o[idx] = f2bf(w[idx]);
    } else {
        int i = tidx;
        float iv;
        iv = rsqrtf(vk[i] + EPS_BN) * gk[i]; sk[i] = iv; tk[i] = bk[i] - mk[i] * iv;
        iv = rsqrtf(vs[i] + EPS_BN) * gs[i]; ss[i] = iv; ts[i] = bs[i] - ms[i] * iv;
        iv = rsqrtf(vh[i] + EPS_BN) * gh[i]; sh[i] = iv; th[i] = bh[i] - mh[i] * iv;
        s5[i] = 1.f; t5[i] = bh2[i];
    }
}

// ---------------------------------------------------------------------------
extern "C" void kernel_launch(void* const* d_in, const int* in_sizes, int n_in,
                              void* d_out, int out_size, void* d_ws, size_t ws_size,
                              hipStream_t stream)
{
    const float* in_kernel = (const float*)d_in[0];
    const float* in_search = (const float*)d_in[1];
    const float* wk  = (const float*)d_in[2];
    const float* gk  = (const float*)d_in[3];
    const float* bk  = (const float*)d_in[4];
    const float* mk  = (const float*)d_in[5];
    const float* vk  = (const float*)d_in[6];
    const float* wsw = (const float*)d_in[7];
    const float* gs  = (const float*)d_in[8];
    const float* bs  = (const float*)d_in[9];
    const float* ms  = (const float*)d_in[10];
    const float* vs  = (const float*)d_in[11];
    const float* wh1 = (const float*)d_in[12];
    const float* gh  = (const float*)d_in[13];
    const float* bh  = (const float*)d_in[14];
    const float* mh  = (const float*)d_in[15];
    const float* vh  = (const float*)d_in[16];
    const float* wh2 = (const float*)d_in[17];
    const float* bh2 = (const float*)d_in[18];
    float* out = (float*)d_out;

    char* w = (char*)d_ws;
    u16* Wk2 = (u16*)w;  w += 1179648;      // 256*2304 bf16
    u16* Ws2 = (u16*)w;  w += 1179648;
    u16* Wh1 = (u16*)w;  w += 131072;       // 256*256 bf16
    u16* Wh2 = (u16*)w;  w += 131072;
    float* sk = (float*)w; w += 1024;
    float* tk = (float*)w; w += 1024;
    float* ss = (float*)w; w += 1024;
    float* ts = (float*)w; w += 1024;
    float* sh = (float*)w; w += 1024;
    float* th = (float*)w; w += 1024;
    float* s5 = (float*)w; w += 1024;
    float* t5 = (float*)w; w += 1024;
    u16* kfeat = (u16*)w; w += 1638400;     // 128*25*256 bf16
    u16* sfeat = (u16*)w; w += 55115776;    // 128*841*256 bf16
    u16* feat  = (u16*)w; w += 40960000;    // 128*625*256 bf16
    u16* ktr   = (u16*)w; w += 3211264;     // 128*49*256 bf16 (NHWC kernel input)
    u16* strA  = (u16*)w; w += 62980096;    // 128*961*256 bf16 (NHWC search input)
    u16* hbuf  = strA;                      // alias: strA dead after stage 2

    tr_all<<<2048 + 128, 256, 0, stream>>>(in_search, in_kernel, strA, ktr);
    prep_all<<<5121, 256, 0, stream>>>(wk, wsw, wh1, wh2,
                                       gk, bk, mk, vk, gs, bs, ms, vs,
                                       gh, bh, mh, vh, bh2,
                                       Wk2, Ws2, Wh1, Wh2,
                                       sk, tk, ss, ts, sh, th, s5, t5);

    // stage 1: kernel tower  -> kfeat NHWC [128*25, 256]  (old structure)
    conv_gemm<9, true, u16, true><<<dim3(2, 25), 256, 0, stream>>>(
        ktr, Wk2, sk, tk, kfeat, 7, 7, 5, 5);
    // stage 2: search tower  -> sfeat NHWC [128*841, 256]
    //   256x256-tile 8-phase pipeline: 421 J-tiles, full M=256 per block.
    conv_gemm8<9><<<dim3(421), 512, 0, stream>>>(
        strA, Ws2, ss, ts, sfeat, 31, 31, 29, 29, 128 * 841);
    // stage 3: depthwise xcorr -> feat NHWC [128*625, 256]
    xcorr_kernel<<<128 * 25, 256, 0, stream>>>(sfeat, kfeat, feat);
    // stage 4: head 1x1 + BN + ReLU -> hbuf NHWC
    conv_gemm<1, true, u16, true><<<dim3(2, 625), 256, 0, stream>>>(
        feat, Wh1, sh, th, hbuf, 25, 25, 25, 25);
    // stage 5: head 1x1 + bias -> out NCHW fp32
    conv_gemm<1, false, float, false><<<dim3(2, 625), 256, 0, stream>>>(
        hbuf, Wh2, s5, t5, out, 25, 25, 25, 25);

    (void)in_sizes; (void)n_in; (void)out_size; (void)ws_size;
}